// Round 10
// baseline (108.026 us; speedup 1.0000x reference)
//
#include <hip/hip_runtime.h>
#include <math.h>

#define BLK  256
#define BLKM 1024

constexpr int N_IMG = 32;
constexpr int P_PRI = 8732;
constexpr int C_CLS = 81;
constexpr int N_OBJ = 24;
constexpr int RPB   = 64;                         // rows per k_main tile (4 lanes/row)
constexpr int PB2   = (P_PRI + RPB - 1) / RPB;    // 137 tiles per image
constexpr int NTIL  = PB2 * N_IMG;                // 4384 tiles
constexpr int GRID  = 2048;                       // persistent blocks (8 per CU)

// ---------------------------------------------------------------------------
// Kernel 1: per (image, object): argmax IoU over priors (first max index).
// Also zeroes npos and the done counter.
// ---------------------------------------------------------------------------
__global__ void k_obj_match(const float* __restrict__ boxes,
                            const float* __restrict__ priors,
                            int* __restrict__ prior_for_obj,
                            int* __restrict__ npos,
                            int* __restrict__ done) {
    const int o = blockIdx.x;
    const int n = blockIdx.y;
    const int tid = threadIdx.x;

    if (o == 0 && tid == 0) npos[n] = 0;
    if (o == 0 && n == 0 && tid == 1) *done = 0;

    const float x1 = boxes[(n * N_OBJ + o) * 4 + 0];
    const float y1 = boxes[(n * N_OBJ + o) * 4 + 1];
    const float x2 = boxes[(n * N_OBJ + o) * 4 + 2];
    const float y2 = boxes[(n * N_OBJ + o) * 4 + 3];
    const float ab = (x2 - x1) * (y2 - y1);

    const float4* pr4 = (const float4*)priors;

    float bv = -1.0f;
    int   bi = P_PRI;
    for (int p = tid; p < P_PRI; p += BLK) {
        const float4 c = pr4[p];
        const float px1 = c.x - c.z / 2.0f, py1 = c.y - c.w / 2.0f;
        const float px2 = c.x + c.z / 2.0f, py2 = c.y + c.w / 2.0f;
        const float pa  = (px2 - px1) * (py2 - py1);
        const float lox = fmaxf(x1, px1), loy = fmaxf(y1, py1);
        const float hix = fminf(x2, px2), hiy = fminf(y2, py2);
        const float iw = fmaxf(hix - lox, 0.0f), ih = fmaxf(hiy - loy, 0.0f);
        const float inter = iw * ih;
        const float iou = inter / (ab + pa - inter);
        if (iou > bv) { bv = iou; bi = p; }            // ascending p keeps first max
    }

    __shared__ float sv[BLK];
    __shared__ int   si[BLK];
    sv[tid] = bv; si[tid] = bi;
    __syncthreads();
    for (int s = BLK / 2; s > 0; s >>= 1) {
        if (tid < s) {
            const float v2 = sv[tid + s]; const int i2 = si[tid + s];
            if (v2 > sv[tid] || (v2 == sv[tid] && i2 < si[tid])) { sv[tid] = v2; si[tid] = i2; }
        }
        __syncthreads();
    }
    if (tid == 0) prior_for_obj[n * N_OBJ + o] = si[0];
}

__device__ __forceinline__ float pick4(const float4 v, int j) {
    return j == 0 ? v.x : (j == 1 ? v.y : (j == 2 ? v.z : v.w));
}

// ---------------------------------------------------------------------------
// Kernel 2: PERSISTENT fused matching + softmax-CE + CIoU. 2048 blocks
// grid-stride over 4384 tiles; body identical to R8 (4 lanes/row, 5x float4
// + scalar col80 per lane, one latency round, match under load latency).
// ---------------------------------------------------------------------------
__global__ void __launch_bounds__(BLK, 4)
k_main(const float* __restrict__ locs,
       const float* __restrict__ scores,
       const float* __restrict__ boxes,
       const int*   __restrict__ labels,
       const float* __restrict__ priors,
       const int*   __restrict__ prior_for_obj,
       float* __restrict__ conf_neg,
       int*   __restrict__ npos,
       float* __restrict__ partial_conf,
       float* __restrict__ partial_loc) {
    __shared__ int   pfo[N_OBJ];
    __shared__ int   slab[N_OBJ];
    __shared__ float wred[4][4];

    const int tid = threadIdx.x;
    const int row = tid >> 2;
    const int q   = tid & 3;
    const int wid = tid >> 6;

    for (int t = blockIdx.x; t < NTIL; t += GRID) {
        const int n  = t / PB2;
        const int r0 = (t - n * PB2) * RPB;
        const int rows = min(RPB, P_PRI - r0);

        __syncthreads();                               // LDS reuse guard
        if (tid < N_OBJ) pfo[tid] = prior_for_obj[n * N_OBJ + tid];
        if (tid >= 64 && tid < 64 + N_OBJ) slab[tid - 64] = labels[n * N_OBJ + (tid - 64)];

        const int p = r0 + row;
        const int psafe = (p < P_PRI) ? p : (P_PRI - 1);

        // ---- issue ALL score loads first: 5x float4 + (lane3) scalar ----
        const float* xrow = scores + (size_t)(n * P_PRI + psafe) * C_CLS;
        float4 v0 = *(const float4*)(xrow + 4 * q);
        float4 v1 = *(const float4*)(xrow + 4 * q + 16);
        float4 v2 = *(const float4*)(xrow + 4 * q + 32);
        float4 v3 = *(const float4*)(xrow + 4 * q + 48);
        float4 v4 = *(const float4*)(xrow + 4 * q + 64);
        const float v80 = (q == 3) ? xrow[80] : 0.0f;

        // ---- prior box (independent load, also early) ----
        const float4 c = ((const float4*)priors)[psafe];
        const float px1 = c.x - c.z / 2.0f, py1 = c.y - c.w / 2.0f;
        const float px2 = c.x + c.z / 2.0f, py2 = c.y + c.w / 2.0f;
        const float pa  = (px2 - px1) * (py2 - py1);

        // ---- match over all 24 boxes (covers the load latency) ----
        const float4* bxg = (const float4*)(boxes + (size_t)n * N_OBJ * 4);
        float bv = -1.0f;
        int   bo = 0;
#pragma unroll
        for (int o = 0; o < N_OBJ; ++o) {
            const float4 b = bxg[o];
            const float lox = fmaxf(b.x, px1), loy = fmaxf(b.y, py1);
            const float hix = fminf(b.z, px2), hiy = fminf(b.w, py2);
            const float iw = fmaxf(hix - lox, 0.0f), ih = fmaxf(hiy - loy, 0.0f);
            const float inter = iw * ih;
            const float ab = (b.z - b.x) * (b.w - b.y);
            const float iou = inter / (ab + pa - inter);
            if (iou > bv) { bv = iou; bo = o; }        // strict > keeps first max
        }
        __syncthreads();                               // pfo/slab visible

        int fo = -1;
#pragma unroll
        for (int o = 0; o < N_OBJ; ++o)
            if (pfo[o] == p) fo = o;                   // ascending: last-writer-wins

        const int   obj = (fo >= 0) ? fo : bo;
        const float ov  = (fo >= 0) ? 1.0f : bv;

        int cls = slab[obj];
        if (ov < 0.5f) cls = 0;

        // ---- exp-sum over this lane's 20 cols (+ col 80 on lane3) ----
        float a0, a1;
        a0  = __expf(v0.x) + __expf(v0.y);
        a1  = __expf(v0.z) + __expf(v0.w);
        a0 += __expf(v1.x) + __expf(v1.y);
        a1 += __expf(v1.z) + __expf(v1.w);
        a0 += __expf(v2.x) + __expf(v2.y);
        a1 += __expf(v2.z) + __expf(v2.w);
        a0 += __expf(v3.x) + __expf(v3.y);
        a1 += __expf(v3.z) + __expf(v3.w);
        a0 += __expf(v4.x) + __expf(v4.y);
        a1 += __expf(v4.z) + __expf(v4.w);
        float s = a0 + a1;
        if (q == 3) s += __expf(v80);
        s += __shfl_xor(s, 1);
        s += __shfl_xor(s, 2);                         // row total in all 4 lanes

        // ---- x[cls]: owner lane extracts statically, quad-broadcast ----
        float sl = 0.0f;
        {
            const int i5 = cls >> 4;
            const int j3 = cls & 3;
            switch (i5) {
                case 0: sl = pick4(v0, j3); break;
                case 1: sl = pick4(v1, j3); break;
                case 2: sl = pick4(v2, j3); break;
                case 3: sl = pick4(v3, j3); break;
                case 4: sl = pick4(v4, j3); break;
                default: sl = v80; break;
            }
        }
        const int owner = (cls >= 80) ? 3 : ((cls >> 2) & 3);
        const float selv = __shfl(sl, (tid & ~3) + owner);

        float confpos = 0.0f, locv = 0.0f;
        int   cnt1 = 0;
        if (q == 0 && row < rows) {
            const float conf = __logf(s) - selv;
            const bool pos = (cls != 0);
            conf_neg[n * P_PRI + p] = pos ? 0.0f : fmaxf(conf, 0.0f);
            if (pos) {
                cnt1 = 1;
                confpos = conf;
                const float4 g = ((const float4*)locs)[(size_t)n * P_PRI + p];
                const float cx = g.x * c.z / 10.0f + c.x;
                const float cy = g.y * c.w / 10.0f + c.y;
                const float w  = __expf(g.z / 5.0f) * c.z;
                const float hh = __expf(g.w / 5.0f) * c.w;
                const float b1x1 = cx - w / 2.0f, b1y1 = cy - hh / 2.0f;
                const float b1x2 = cx + w / 2.0f, b1y2 = cy + hh / 2.0f;

                const float4 tb = bxg[obj];
                const float w1 = b1x2 - b1x1, h1 = b1y2 - b1y1;
                const float w2 = tb.z - tb.x, h2 = tb.w - tb.y;
                const float area1 = w1 * h1,  area2 = w2 * h2;
                const float c1x = (b1x2 + b1x1) / 2.0f, c1y = (b1y2 + b1y1) / 2.0f;
                const float c2x = (tb.z + tb.x) / 2.0f, c2y = (tb.w + tb.y) / 2.0f;
                const float inw = fmaxf(fminf(b1x2, tb.z) - fmaxf(b1x1, tb.x), 0.0f);
                const float inh = fmaxf(fminf(b1y2, tb.w) - fmaxf(b1y1, tb.y), 0.0f);
                const float owd = fmaxf(fmaxf(b1x2, tb.z) - fminf(b1x1, tb.x), 0.0f);
                const float ohd = fmaxf(fmaxf(b1y2, tb.w) - fminf(b1y1, tb.y), 0.0f);
                const float inner_diag = (c2x - c1x) * (c2x - c1x) + (c2y - c1y) * (c2y - c1y);
                const float outer_diag = owd * owd + ohd * ohd;
                const float inner = inw * inh;
                const float iou = inner / (area1 + area2 - inner);
                const float K = 0.40528473456935108577551785283891f; // 4/pi^2
                const float dat = atanf(w2 / h2) - atanf(w1 / h1);
                const float vv = K * dat * dat;
                const float alpha = vv / (1.0f - iou + vv);
                locv = 1.0f - iou + inner_diag / outer_diag + alpha * vv;
            }
        }

        // ---- block reduction: shfl within wave, tiny LDS across 4 waves ----
#pragma unroll
        for (int off = 32; off > 0; off >>= 1) {
            confpos += __shfl_down(confpos, off);
            locv    += __shfl_down(locv, off);
            cnt1    += __shfl_down(cnt1, off);
        }
        if ((tid & 63) == 0) {
            wred[wid][0] = confpos; wred[wid][1] = locv; wred[wid][2] = (float)cnt1;
        }
        __syncthreads();
        if (tid == 0) {
            float a = 0.0f, b = 0.0f, d = 0.0f;
#pragma unroll
            for (int w2 = 0; w2 < 4; ++w2) { a += wred[w2][0]; b += wred[w2][1]; d += wred[w2][2]; }
            partial_conf[t] = a;
            partial_loc [t] = b;
            atomicAdd(&npos[n], (int)d);
        }
    }
}

// ---------------------------------------------------------------------------
// Kernel 3: per image, exact top-k sum of conf_neg (k=3*n_pos) via 31-round
// bitwise radix-select (registers + ballot/popc). Last block also does the
// final scalar reduction.
// ---------------------------------------------------------------------------
__global__ void __launch_bounds__(BLKM)
k_mine(const float* __restrict__ conf_neg,
       const int*   __restrict__ npos,
       float* __restrict__ hardneg,
       const float* __restrict__ partial_conf,
       const float* __restrict__ partial_loc,
       int* __restrict__ done,
       float* __restrict__ out) {
    __shared__ int   wcnt[2][BLKM / 64];
    __shared__ float wsum[BLKM / 64];
    __shared__ float fs1[BLKM / 64], fs2[BLKM / 64], fs3[BLKM / 64];
    __shared__ int   fi[BLKM / 64];
    __shared__ bool  amLast;

    const int n    = blockIdx.x;
    const int tid  = threadIdx.x;
    const int wid  = tid >> 6;
    const int lane = tid & 63;

    unsigned v[9];
#pragma unroll
    for (int k = 0; k < 9; ++k) {
        const int p = tid + k * BLKM;
        v[k] = (p < P_PRI) ? __float_as_uint(conf_neg[n * P_PRI + p]) : 0u;
    }

    int k0 = 3 * npos[n];
    if (k0 > P_PRI) k0 = P_PRI;

    float result = 0.0f;
    if (k0 > 0) {
        unsigned prefix = 0u;
        int kk = k0;
        for (int bit = 30; bit >= 0; --bit) {          // bit31 (sign) always 0
            const unsigned hi = (prefix >> bit) | 1u;
            int cnt = 0;
#pragma unroll
            for (int k = 0; k < 9; ++k)
                cnt += __popcll(__ballot((v[k] >> bit) == hi));
            if (lane == 0) wcnt[bit & 1][wid] = cnt;
            __syncthreads();
            int tot = 0;
#pragma unroll
            for (int w = 0; w < BLKM / 64; ++w) tot += wcnt[bit & 1][w];
            if (tot >= kk) prefix |= (1u << bit);
            else           kk -= tot;
        }

        float psum = 0.0f; int pcnt = 0;
#pragma unroll
        for (int k = 0; k < 9; ++k) {
            if (v[k] > prefix) { psum += __uint_as_float(v[k]); ++pcnt; }
        }
#pragma unroll
        for (int off = 32; off > 0; off >>= 1) {
            psum += __shfl_down(psum, off);
            pcnt += __shfl_down(pcnt, off);
        }
        __syncthreads();
        if (lane == 0) { wsum[wid] = psum; wcnt[0][wid] = pcnt; }
        __syncthreads();
        if (tid == 0) {
            float S = 0.0f; int C = 0;
#pragma unroll
            for (int w = 0; w < BLKM / 64; ++w) { S += wsum[w]; C += wcnt[0][w]; }
            result = S + (float)(k0 - C) * __uint_as_float(prefix);
        }
    }
    if (tid == 0) hardneg[n] = result;

    // ---- last block performs the final scalar reduction ----
    __threadfence();
    if (tid == 0) amLast = (atomicAdd(done, 1) == N_IMG - 1);
    __syncthreads();
    if (!amLast) return;
    __threadfence();

    float c = 0.0f, l = 0.0f, h = 0.0f;
    int np = 0;
    for (int i = tid; i < NTIL; i += BLKM) { c += partial_conf[i]; l += partial_loc[i]; }
    if (tid < N_IMG) { h = hardneg[tid]; np = npos[tid]; }
#pragma unroll
    for (int off = 32; off > 0; off >>= 1) {
        c  += __shfl_down(c, off);
        l  += __shfl_down(l, off);
        h  += __shfl_down(h, off);
        np += __shfl_down(np, off);
    }
    if (lane == 0) { fs1[wid] = c; fs2[wid] = l; fs3[wid] = h; fi[wid] = np; }
    __syncthreads();
    if (tid == 0) {
        float C = 0.0f, L = 0.0f, H = 0.0f; int NP = 0;
#pragma unroll
        for (int w = 0; w < BLKM / 64; ++w) { C += fs1[w]; L += fs2[w]; H += fs3[w]; NP += fi[w]; }
        const float npt = (float)NP;
        out[0] = (H + C) / npt + L / npt;   // conf_loss + ALPHA * loc_loss
    }
}

// ---------------------------------------------------------------------------
extern "C" void kernel_launch(void* const* d_in, const int* in_sizes, int n_in,
                              void* d_out, int out_size, void* d_ws, size_t ws_size,
                              hipStream_t stream) {
    const float* locs   = (const float*)d_in[0];  // [N,P,4]
    const float* scores = (const float*)d_in[1];  // [N,P,C]
    const float* boxes  = (const float*)d_in[2];  // [N,NOBJ,4]
    const int*   labels = (const int*)  d_in[3];  // [N,NOBJ]
    const float* priors = (const float*)d_in[4];  // [P,4]
    float* out = (float*)d_out;

    char* w = (char*)d_ws;
    float* conf_neg      = (float*)w; w += (size_t)N_IMG * P_PRI * 4;
    int*   prior_for_obj = (int*)w;   w += (size_t)N_IMG * N_OBJ * 4;
    int*   npos          = (int*)w;   w += (size_t)N_IMG * 4;
    float* partial_conf  = (float*)w; w += (size_t)NTIL * 4;
    float* partial_loc   = (float*)w; w += (size_t)NTIL * 4;
    float* hardneg       = (float*)w; w += (size_t)N_IMG * 4;
    int*   done          = (int*)w;   w += 64;

    dim3 gridO(N_OBJ, N_IMG);
    k_obj_match<<<gridO, BLK, 0, stream>>>(boxes, priors, prior_for_obj, npos, done);

    k_main<<<GRID, BLK, 0, stream>>>(locs, scores, boxes, labels, priors,
                                     prior_for_obj, conf_neg, npos,
                                     partial_conf, partial_loc);

    k_mine<<<N_IMG, BLKM, 0, stream>>>(conf_neg, npos, hardneg,
                                       partial_conf, partial_loc, done, out);
}

// Round 11
// 82.654 us; speedup vs baseline: 1.3070x; 1.3070x over previous
//
#include <hip/hip_runtime.h>
#include <math.h>

#define BLK   256
#define BLKM  1024
#define BLKP  1024

constexpr int N_IMG = 32;
constexpr int P_PRI = 8732;
constexpr int C_CLS = 81;
constexpr int N_OBJ = 24;
constexpr int CROW  = 128;                        // rows per chunk
constexpr int CPI   = (P_PRI + CROW - 1) / CROW;  // 69 chunks per image
constexpr int NCH   = CPI * N_IMG;                // 2208 chunks
constexpr int GRIDM = 256;                        // persistent k_main blocks (1/CU)
constexpr int ROWB  = C_CLS * 4;                  // 324 B per row
constexpr int LBUF  = 42 * 1024;                  // padded LDS buffer (41 loads overrun-safe)

// ---------------------------------------------------------------------------
// Kernel 1: per (image, object): argmax IoU over priors (first max index).
// Also zeroes npos and the done counter.
// ---------------------------------------------------------------------------
__global__ void k_obj_match(const float* __restrict__ boxes,
                            const float* __restrict__ priors,
                            int* __restrict__ prior_for_obj,
                            int* __restrict__ npos,
                            int* __restrict__ done) {
    const int o = blockIdx.x;
    const int n = blockIdx.y;
    const int tid = threadIdx.x;

    if (o == 0 && tid == 0) npos[n] = 0;
    if (o == 0 && n == 0 && tid == 1) *done = 0;

    const float x1 = boxes[(n * N_OBJ + o) * 4 + 0];
    const float y1 = boxes[(n * N_OBJ + o) * 4 + 1];
    const float x2 = boxes[(n * N_OBJ + o) * 4 + 2];
    const float y2 = boxes[(n * N_OBJ + o) * 4 + 3];
    const float ab = (x2 - x1) * (y2 - y1);

    const float4* pr4 = (const float4*)priors;

    float bv = -1.0f;
    int   bi = P_PRI;
    for (int p = tid; p < P_PRI; p += BLK) {
        const float4 c = pr4[p];
        const float px1 = c.x - c.z / 2.0f, py1 = c.y - c.w / 2.0f;
        const float px2 = c.x + c.z / 2.0f, py2 = c.y + c.w / 2.0f;
        const float pa  = (px2 - px1) * (py2 - py1);
        const float lox = fmaxf(x1, px1), loy = fmaxf(y1, py1);
        const float hix = fminf(x2, px2), hiy = fminf(y2, py2);
        const float iw = fmaxf(hix - lox, 0.0f), ih = fmaxf(hiy - loy, 0.0f);
        const float inter = iw * ih;
        const float iou = inter / (ab + pa - inter);
        if (iou > bv) { bv = iou; bi = p; }            // ascending p keeps first max
    }

    __shared__ float sv[BLK];
    __shared__ int   si[BLK];
    sv[tid] = bv; si[tid] = bi;
    __syncthreads();
    for (int s = BLK / 2; s > 0; s >>= 1) {
        if (tid < s) {
            const float v2 = sv[tid + s]; const int i2 = si[tid + s];
            if (v2 > sv[tid] || (v2 == sv[tid] && i2 < si[tid])) { sv[tid] = v2; si[tid] = i2; }
        }
        __syncthreads();
    }
    if (tid == 0) prior_for_obj[n * N_OBJ + o] = si[0];
}

// ---------------------------------------------------------------------------
// Async DMA stage of one chunk into LDS. 1024-B per wave-instruction.
// LDS dest is wave-uniform base + lane*16 (hardware); global src per-lane.
// ---------------------------------------------------------------------------
__device__ __forceinline__ void stage_chunk(const char* gb, char* lb, int nloads,
                                            int clampv, int wv, int lane) {
    for (int i = wv; i < nloads; i += BLKP / 64) {
        int off = i * 1024 + lane * 16;
        if (clampv >= 0) off = min(off, clampv);
        __builtin_amdgcn_global_load_lds(
            (const __attribute__((address_space(1))) void*)(gb + off),
            (__attribute__((address_space(3))) void*)(lb + i * 1024),
            16, 0, 0);
    }
}

// ---------------------------------------------------------------------------
// Kernel 2: persistent, double-buffered DMA-staged fused kernel.
// 256 blocks x 1024 threads; each block owns ~9 contiguous 128-row chunks.
// Per chunk: DMA next chunk || compute current from LDS (8 lanes/row).
// ---------------------------------------------------------------------------
__global__ void __launch_bounds__(BLKP)
k_main(const float* __restrict__ locs,
       const float* __restrict__ scores,
       const float* __restrict__ boxes,
       const int*   __restrict__ labels,
       const float* __restrict__ priors,
       const int*   __restrict__ prior_for_obj,
       float* __restrict__ conf_neg,
       int*   __restrict__ npos,
       float* __restrict__ partial_conf,
       float* __restrict__ partial_loc) {
    __shared__ char   sbuf[2][LBUF];               // 84 KB
    __shared__ float4 sbx[2][N_OBJ];
    __shared__ int    spfo[2][N_OBJ];
    __shared__ int    sslab[2][N_OBJ];
    __shared__ float  wredf[16][2];
    __shared__ int    wredi[16][2];

    const int tid  = threadIdx.x;
    const int lane = tid & 63;
    const int wv   = tid >> 6;
    const int b    = blockIdx.x;

    const int c0 = (b * NCH) / GRIDM;
    const int c1 = ((b + 1) * NCH) / GRIDM;        // 8-9 chunks, spans <=2 images
    const int nA = c0 / CPI;
    const int nB = (c1 - 1) / CPI;

    if (tid < N_OBJ) {
        sbx [0][tid] = ((const float4*)boxes)[nA * N_OBJ + tid];
        spfo[0][tid] = prior_for_obj[nA * N_OBJ + tid];
        sslab[0][tid] = labels[nA * N_OBJ + tid];
    } else if (tid < 2 * N_OBJ) {
        const int t2 = tid - N_OBJ;
        sbx [1][t2] = ((const float4*)boxes)[nB * N_OBJ + t2];
        spfo[1][t2] = prior_for_obj[nB * N_OBJ + t2];
        sslab[1][t2] = labels[nB * N_OBJ + t2];
    }

    // prologue: stage first chunk into buf0
    {
        const int n = c0 / CPI, r0 = (c0 - n * CPI) * CROW;
        const int rows = min(CROW, P_PRI - r0);
        const char* gb = (const char*)scores + ((size_t)n * P_PRI + r0) * (size_t)ROWB;
        stage_chunk(gb, &sbuf[0][0], (rows == CROW) ? 41 : 9,
                    (c0 == NCH - 1) ? rows * ROWB - 16 : -1, wv, lane);
    }
    __syncthreads();                               // vmcnt(0) drain + meta visible

    float accC = 0.0f, accL = 0.0f;
    int   cntA = 0, cntB = 0;
    int   cur = 0;

    const int row = tid >> 3;                      // 0..127
    const int q   = tid & 7;                       // 8 lanes per row

    for (int c = c0; c < c1; ++c) {
        const int n  = c / CPI;
        const int r0 = (c - n * CPI) * CROW;
        const int rows = min(CROW, P_PRI - r0);
        const int mI = (n == nA) ? 0 : 1;

        // ---- issue DMA for next chunk into the other buffer ----
        if (c + 1 < c1) {
            const int n2 = (c + 1) / CPI, r02 = ((c + 1) - n2 * CPI) * CROW;
            const int rows2 = min(CROW, P_PRI - r02);
            const char* gb2 = (const char*)scores + ((size_t)n2 * P_PRI + r02) * (size_t)ROWB;
            stage_chunk(gb2, &sbuf[cur ^ 1][0], (rows2 == CROW) ? 41 : 9,
                        (c + 1 == NCH - 1) ? rows2 * ROWB - 16 : -1, wv, lane);
        }

        // ---- compute current chunk from LDS ----
        const float* bf = (const float*)&sbuf[cur][0];
        const bool rv = (row < rows);
        const int p = r0 + row;
        const int psafe = rv ? p : (P_PRI - 1);

        float v[10];
#pragma unroll
        for (int i = 0; i < 10; ++i) v[i] = bf[row * 81 + q + 8 * i];
        const float v80 = bf[row * 81 + 80];

        const float4 cpri = ((const float4*)priors)[psafe];
        const float px1 = cpri.x - cpri.z / 2.0f, py1 = cpri.y - cpri.w / 2.0f;
        const float px2 = cpri.x + cpri.z / 2.0f, py2 = cpri.y + cpri.w / 2.0f;
        const float pa  = (px2 - px1) * (py2 - py1);

        // match: 3 objects per lane, first-max combine over 8 lanes
        float bv = -1.0f;
        int   bo = q * 3;
#pragma unroll
        for (int j = 0; j < 3; ++j) {
            const int o = q * 3 + j;
            const float4 bb = sbx[mI][o];
            const float lox = fmaxf(bb.x, px1), loy = fmaxf(bb.y, py1);
            const float hix = fminf(bb.z, px2), hiy = fminf(bb.w, py2);
            const float iw = fmaxf(hix - lox, 0.0f), ih = fmaxf(hiy - loy, 0.0f);
            const float inter = iw * ih;
            const float ab = (bb.z - bb.x) * (bb.w - bb.y);
            const float iou = inter / (ab + pa - inter);
            if (iou > bv) { bv = iou; bo = o; }        // ascending keeps first max
        }
#pragma unroll
        for (int mm = 1; mm < 8; mm <<= 1) {
            const float v2 = __shfl_xor(bv, mm);
            const int   o2 = __shfl_xor(bo, mm);
            if (v2 > bv || (v2 == bv && o2 < bo)) { bv = v2; bo = o2; }
        }

        int fo = -1;
#pragma unroll
        for (int j = 0; j < 3; ++j) {
            const int o = q * 3 + j;
            if (spfo[mI][o] == p) fo = o;              // ascending: last-writer-wins
        }
#pragma unroll
        for (int mm = 1; mm < 8; mm <<= 1) fo = max(fo, __shfl_xor(fo, mm));

        const int   obj = (fo >= 0) ? fo : bo;
        const float ov  = (fo >= 0) ? 1.0f : bv;

        int cls = sslab[mI][obj];
        if (ov < 0.5f || !rv) cls = 0;

        // exp-sum + x[cls] selection
        float a0 = 0.0f, a1 = 0.0f, sel = 0.0f;
#pragma unroll
        for (int i = 0; i < 10; ++i) {
            const int col = q + 8 * i;
            const float e = __expf(v[i]);
            if (i & 1) a1 += e; else a0 += e;
            sel += (col == cls) ? v[i] : 0.0f;
        }
        float s = a0 + a1;
        if (q == 0) {
            s += __expf(v80);
            sel += (cls == 80) ? v80 : 0.0f;
        }
#pragma unroll
        for (int mm = 1; mm < 8; mm <<= 1) {
            s   += __shfl_xor(s, mm);
            sel += __shfl_xor(sel, mm);
        }

        int cnt1 = 0;
        if (q == 0 && rv) {
            const float conf = __logf(s) - sel;
            const bool pos = (cls != 0);
            conf_neg[n * P_PRI + p] = pos ? 0.0f : fmaxf(conf, 0.0f);
            if (pos) {
                cnt1 = 1;
                accC += conf;
                const float4 g = ((const float4*)locs)[(size_t)n * P_PRI + p];
                const float cx = g.x * cpri.z / 10.0f + cpri.x;
                const float cy = g.y * cpri.w / 10.0f + cpri.y;
                const float w  = __expf(g.z / 5.0f) * cpri.z;
                const float hh = __expf(g.w / 5.0f) * cpri.w;
                const float b1x1 = cx - w / 2.0f, b1y1 = cy - hh / 2.0f;
                const float b1x2 = cx + w / 2.0f, b1y2 = cy + hh / 2.0f;

                const float4 tb = sbx[mI][obj];
                const float w1 = b1x2 - b1x1, h1 = b1y2 - b1y1;
                const float w2 = tb.z - tb.x, h2 = tb.w - tb.y;
                const float area1 = w1 * h1,  area2 = w2 * h2;
                const float c1x = (b1x2 + b1x1) / 2.0f, c1y = (b1y2 + b1y1) / 2.0f;
                const float c2x = (tb.z + tb.x) / 2.0f, c2y = (tb.w + tb.y) / 2.0f;
                const float inw = fmaxf(fminf(b1x2, tb.z) - fmaxf(b1x1, tb.x), 0.0f);
                const float inh = fmaxf(fminf(b1y2, tb.w) - fmaxf(b1y1, tb.y), 0.0f);
                const float owd = fmaxf(fmaxf(b1x2, tb.z) - fminf(b1x1, tb.x), 0.0f);
                const float ohd = fmaxf(fmaxf(b1y2, tb.w) - fminf(b1y1, tb.y), 0.0f);
                const float inner_diag = (c2x - c1x) * (c2x - c1x) + (c2y - c1y) * (c2y - c1y);
                const float outer_diag = owd * owd + ohd * ohd;
                const float inner = inw * inh;
                const float iou = inner / (area1 + area2 - inner);
                const float K = 0.40528473456935108577551785283891f; // 4/pi^2
                const float dat = atanf(w2 / h2) - atanf(w1 / h1);
                const float vv = K * dat * dat;
                const float alpha = vv / (1.0f - iou + vv);
                accL += 1.0f - iou + inner_diag / outer_diag + alpha * vv;
            }
        }
        if (mI == 0) cntA += cnt1; else cntB += cnt1;

        cur ^= 1;
        __syncthreads();   // vmcnt(0): next-chunk DMA landed; all waves done with old buf
    }

    // ---- block-end reduction (once) ----
#pragma unroll
    for (int off = 32; off > 0; off >>= 1) {
        accC += __shfl_down(accC, off);
        accL += __shfl_down(accL, off);
        cntA += __shfl_down(cntA, off);
        cntB += __shfl_down(cntB, off);
    }
    if (lane == 0) { wredf[wv][0] = accC; wredf[wv][1] = accL;
                     wredi[wv][0] = cntA; wredi[wv][1] = cntB; }
    __syncthreads();
    if (tid == 0) {
        float C = 0.0f, L = 0.0f; int A = 0, B2 = 0;
#pragma unroll
        for (int w2 = 0; w2 < 16; ++w2) { C += wredf[w2][0]; L += wredf[w2][1];
                                          A += wredi[w2][0]; B2 += wredi[w2][1]; }
        partial_conf[b] = C;
        partial_loc [b] = L;
        atomicAdd(&npos[nA], A);
        if (nB != nA) atomicAdd(&npos[nB], B2);
    }
}

// ---------------------------------------------------------------------------
// Kernel 3: per image, exact top-k sum of conf_neg (k=3*n_pos) via 31-round
// bitwise radix-select (registers + ballot/popc). Last block also does the
// final scalar reduction.
// ---------------------------------------------------------------------------
__global__ void __launch_bounds__(BLKM)
k_mine(const float* __restrict__ conf_neg,
       const int*   __restrict__ npos,
       float* __restrict__ hardneg,
       const float* __restrict__ partial_conf,
       const float* __restrict__ partial_loc,
       int* __restrict__ done,
       float* __restrict__ out) {
    __shared__ int   wcnt[2][BLKM / 64];
    __shared__ float wsum[BLKM / 64];
    __shared__ float fs1[BLKM / 64], fs2[BLKM / 64], fs3[BLKM / 64];
    __shared__ int   fi[BLKM / 64];
    __shared__ bool  amLast;

    const int n    = blockIdx.x;
    const int tid  = threadIdx.x;
    const int wid  = tid >> 6;
    const int lane = tid & 63;

    unsigned v[9];
#pragma unroll
    for (int k = 0; k < 9; ++k) {
        const int p = tid + k * BLKM;
        v[k] = (p < P_PRI) ? __float_as_uint(conf_neg[n * P_PRI + p]) : 0u;
    }

    int k0 = 3 * npos[n];
    if (k0 > P_PRI) k0 = P_PRI;

    float result = 0.0f;
    if (k0 > 0) {
        unsigned prefix = 0u;
        int kk = k0;
        for (int bit = 30; bit >= 0; --bit) {
            const unsigned hi = (prefix >> bit) | 1u;
            int cnt = 0;
#pragma unroll
            for (int k = 0; k < 9; ++k)
                cnt += __popcll(__ballot((v[k] >> bit) == hi));
            if (lane == 0) wcnt[bit & 1][wid] = cnt;
            __syncthreads();
            int tot = 0;
#pragma unroll
            for (int w = 0; w < BLKM / 64; ++w) tot += wcnt[bit & 1][w];
            if (tot >= kk) prefix |= (1u << bit);
            else           kk -= tot;
        }

        float psum = 0.0f; int pcnt = 0;
#pragma unroll
        for (int k = 0; k < 9; ++k) {
            if (v[k] > prefix) { psum += __uint_as_float(v[k]); ++pcnt; }
        }
#pragma unroll
        for (int off = 32; off > 0; off >>= 1) {
            psum += __shfl_down(psum, off);
            pcnt += __shfl_down(pcnt, off);
        }
        __syncthreads();
        if (lane == 0) { wsum[wid] = psum; wcnt[0][wid] = pcnt; }
        __syncthreads();
        if (tid == 0) {
            float S = 0.0f; int C = 0;
#pragma unroll
            for (int w = 0; w < BLKM / 64; ++w) { S += wsum[w]; C += wcnt[0][w]; }
            result = S + (float)(k0 - C) * __uint_as_float(prefix);
        }
    }
    if (tid == 0) hardneg[n] = result;

    // ---- last block performs the final scalar reduction ----
    __threadfence();
    if (tid == 0) amLast = (atomicAdd(done, 1) == N_IMG - 1);
    __syncthreads();
    if (!amLast) return;
    __threadfence();

    float c = 0.0f, l = 0.0f, h = 0.0f;
    int np = 0;
    for (int i = tid; i < GRIDM; i += BLKM) { c += partial_conf[i]; l += partial_loc[i]; }
    if (tid < N_IMG) { h = hardneg[tid]; np = npos[tid]; }
#pragma unroll
    for (int off = 32; off > 0; off >>= 1) {
        c  += __shfl_down(c, off);
        l  += __shfl_down(l, off);
        h  += __shfl_down(h, off);
        np += __shfl_down(np, off);
    }
    if (lane == 0) { fs1[wid] = c; fs2[wid] = l; fs3[wid] = h; fi[wid] = np; }
    __syncthreads();
    if (tid == 0) {
        float C = 0.0f, L = 0.0f, H = 0.0f; int NP = 0;
#pragma unroll
        for (int w = 0; w < BLKM / 64; ++w) { C += fs1[w]; L += fs2[w]; H += fs3[w]; NP += fi[w]; }
        const float npt = (float)NP;
        out[0] = (H + C) / npt + L / npt;   // conf_loss + ALPHA * loc_loss
    }
}

// ---------------------------------------------------------------------------
extern "C" void kernel_launch(void* const* d_in, const int* in_sizes, int n_in,
                              void* d_out, int out_size, void* d_ws, size_t ws_size,
                              hipStream_t stream) {
    const float* locs   = (const float*)d_in[0];  // [N,P,4]
    const float* scores = (const float*)d_in[1];  // [N,P,C]
    const float* boxes  = (const float*)d_in[2];  // [N,NOBJ,4]
    const int*   labels = (const int*)  d_in[3];  // [N,NOBJ]
    const float* priors = (const float*)d_in[4];  // [P,4]
    float* out = (float*)d_out;

    char* w = (char*)d_ws;
    float* conf_neg      = (float*)w; w += (size_t)N_IMG * P_PRI * 4;
    int*   prior_for_obj = (int*)w;   w += (size_t)N_IMG * N_OBJ * 4;
    int*   npos          = (int*)w;   w += (size_t)N_IMG * 4;
    float* partial_conf  = (float*)w; w += (size_t)GRIDM * 4;
    float* partial_loc   = (float*)w; w += (size_t)GRIDM * 4;
    float* hardneg       = (float*)w; w += (size_t)N_IMG * 4;
    int*   done          = (int*)w;   w += 64;

    dim3 gridO(N_OBJ, N_IMG);
    k_obj_match<<<gridO, BLK, 0, stream>>>(boxes, priors, prior_for_obj, npos, done);

    k_main<<<GRIDM, BLKP, 0, stream>>>(locs, scores, boxes, labels, priors,
                                       prior_for_obj, conf_neg, npos,
                                       partial_conf, partial_loc);

    k_mine<<<N_IMG, BLKM, 0, stream>>>(conf_neg, npos, hardneg,
                                       partial_conf, partial_loc, done, out);
}